// Round 6
// baseline (649.168 us; speedup 1.0000x reference)
//
#include <hip/hip_runtime.h>
#include <hip/hip_fp16.h>

#define E_EDGES 102400
#define N_NODES 100000
#define G_GRAPHS 64
#define D_EDGE 256
#define D_NODE 256
#define D_GLOB 128
#define KNB 4
#define D_IN 1408   // 256 + 4*256 + 128
#define H1D 512
#define H2D 512
#define H3D 256
#define LN_EPS 1e-3f

typedef _Float16 half8 __attribute__((ext_vector_type(8)));
typedef float f32x4 __attribute__((ext_vector_type(4)));

// async global->LDS, 16B per lane; LDS dest wave-uniform base, HW adds lane*16
__device__ __forceinline__ void gload16(const void* g, void* l) {
    __builtin_amdgcn_global_load_lds((const __attribute__((address_space(1))) void*)g,
                                     (__attribute__((address_space(3))) void*)l, 16, 0, 0);
}

// ---------------- prep kernels ----------------

__global__ void k_prefix(const int* __restrict__ num, int* __restrict__ prefix) {
    if (threadIdx.x == 0) {
        int acc = 0;
        prefix[0] = 0;
        for (int g = 0; g < G_GRAPHS; ++g) { acc += num[g]; prefix[g + 1] = acc; }
    }
}

__global__ void k_gid(const int* __restrict__ prefix, int* __restrict__ gid) {
    int e = blockIdx.x * blockDim.x + threadIdx.x;
    if (e >= E_EDGES) return;
    int lo = 0, hi = G_GRAPHS;
    while (hi - lo > 1) {
        int mid = (lo + hi) >> 1;
        if (e >= prefix[mid]) lo = mid; else hi = mid;
    }
    gid[e] = lo;
}

// dst[n*Ks + k] = (f16) src[k*Ns + n]   (transpose + fp32->f16)
__global__ void k_transpose(const float* __restrict__ src, _Float16* __restrict__ dst,
                            int Ks, int Ns) {
    long total = (long)Ks * Ns;
    for (long idx = (long)blockIdx.x * blockDim.x + threadIdx.x; idx < total;
         idx += (long)gridDim.x * blockDim.x) {
        int n = (int)(idx / Ks);
        int k = (int)(idx - (long)n * Ks);
        dst[idx] = (_Float16)src[(long)k * Ns + n];
    }
}

// f32 -> f16 elementwise, 8 elems/thread-iter
__global__ void k_cvt16(const float* __restrict__ src, _Float16* __restrict__ dst, long n8) {
    for (long i = (long)blockIdx.x * blockDim.x + threadIdx.x; i < n8;
         i += (long)gridDim.x * blockDim.x) {
        float4 u = reinterpret_cast<const float4*>(src)[i * 2];
        float4 v = reinterpret_cast<const float4*>(src)[i * 2 + 1];
        half8 h;
        h[0] = (_Float16)u.x; h[1] = (_Float16)u.y; h[2] = (_Float16)u.z; h[3] = (_Float16)u.w;
        h[4] = (_Float16)v.x; h[5] = (_Float16)v.y; h[6] = (_Float16)v.z; h[7] = (_Float16)v.w;
        reinterpret_cast<half8*>(dst)[i] = h;
    }
}

// ---------------- 8-phase pipelined GEMM: [E,KD] x Wt[512,KD] -> relu -> out[E,512] f16 ----
// BM=256 BN=256 BK=64, 512 thr = 8 waves (2M x 4N), wave tile 128x64, acc[8][4].
// LDS: 2 dbuf x 64KB; per dbuf: A units a0..a3 (64 rows x 128B each, off u*8KB),
//                               B units b0..b3 (off 32KB + u*8KB).
// Per K-tile (dbuf = kt&1): 4 phases. Phase p reads A m-pair {6-2p,7-2p} (descending ->
// a_hi freed after p1, a_lo after p3); B all read at p0 and held in regs.
// Stage schedule (post-barrier, 2 units/phase, all regions' readers finished >=1 phase ago):
//   p0: (kt+1).a0,a2 -> other dbuf      p1: (kt+2).b0,b1 -> this dbuf
//   p2: (kt+2).b2,b3 -> this dbuf       p3: (kt+2).a1,a3 -> this dbuf
// vmcnt(6) once per tile (before p3's closing barrier): forces everything except the
// newest 3 units (next-next tile's) complete -> tile kt+1 fully landed before its reads.
// T2 swizzle: LDS linear, global source slot pre-permuted (slot ^ row&7), ds_read same XOR.

template <int KD, bool GATHER>
__global__ __launch_bounds__(512, 2) void k_gemm8(
    const _Float16* __restrict__ A,
    const _Float16* __restrict__ feat16, const _Float16* __restrict__ nodes16,
    const _Float16* __restrict__ gfeat16,
    const int* __restrict__ ind, const int* __restrict__ gid,
    const _Float16* __restrict__ Wt,
    const float* __restrict__ bias, _Float16* __restrict__ out) {
    constexpr int NT = KD / 64;
    __shared__ __align__(16) char lds[131072];

    const int t = threadIdx.x;
    const int bn = blockIdx.x, bm = blockIdx.y;
    const int n0 = bn * 256;
    const int w = t >> 6, lane = t & 63;
    const int wr = w >> 2, wc = w & 3;          // 2M x 4N
    const int lr = lane & 15, lk = lane >> 4;

    // staging: unit = 64 rows x 64 halves; thread covers (srow, slot)
    const int srow = t >> 3;                    // 0..63
    const int gslot = (t & 7) ^ (srow & 7);     // pre-swizzled global slot
    const int ldst = w * 1024;                  // wave-uniform LDS offset within unit

    // gather metadata: unit u covers edges bm*256 + u*64 + srow
    int e0 = 0, e1 = 0, e2 = 0, e3 = 0, g0 = 0, g1 = 0, g2 = 0, g3 = 0;
    int4 v0, v1, v2, v3;
    if constexpr (GATHER) {
        e0 = bm * 256 + srow; e1 = e0 + 64; e2 = e0 + 128; e3 = e0 + 192;
        v0 = *reinterpret_cast<const int4*>(ind + (size_t)e0 * KNB);
        v1 = *reinterpret_cast<const int4*>(ind + (size_t)e1 * KNB);
        v2 = *reinterpret_cast<const int4*>(ind + (size_t)e2 * KNB);
        v3 = *reinterpret_cast<const int4*>(ind + (size_t)e3 * KNB);
        g0 = gid[e0]; g1 = gid[e1]; g2 = gid[e2]; g3 = gid[e3];
    }

    auto stageA = [&](int kt, int u, char* db) {
        const _Float16* s;
        if constexpr (GATHER) {
            const int e = (u == 0 ? e0 : u == 1 ? e1 : u == 2 ? e2 : e3);
            if (kt < 4) {
                s = feat16 + (size_t)e * D_EDGE + kt * 64;
            } else if (kt < 20) {
                const int4 iv = (u == 0 ? v0 : u == 1 ? v1 : u == 2 ? v2 : v3);
                int j = (kt - 4) >> 2;
                int nid = j == 0 ? iv.x : j == 1 ? iv.y : j == 2 ? iv.z : iv.w;
                s = nodes16 + (size_t)nid * D_NODE + ((kt - 4) & 3) * 64;
            } else {
                const int g = (u == 0 ? g0 : u == 1 ? g1 : u == 2 ? g2 : g3);
                s = gfeat16 + (size_t)g * D_GLOB + (kt - 20) * 64;
            }
        } else {
            s = A + (size_t)(bm * 256 + u * 64 + srow) * KD + kt * 64;
        }
        gload16(s + gslot * 8, db + u * 8192 + ldst);
    };
    auto stageB = [&](int kt, int u, char* db) {
        const _Float16* s = Wt + (size_t)(n0 + u * 64 + srow) * KD + kt * 64;
        gload16(s + gslot * 8, db + 32768 + u * 8192 + ldst);
    };

    f32x4 acc[8][4];
#pragma unroll
    for (int m = 0; m < 8; m++)
#pragma unroll
        for (int n = 0; n < 4; n++) acc[m][n] = (f32x4)0.f;

    char* d0 = lds;
    char* d1 = lds + 65536;

    // prologue: t0 fully; t1 all but a0,a2 (those staged at tile0's p0)
    stageB(0, 0, d0); stageB(0, 1, d0); stageB(0, 2, d0); stageB(0, 3, d0);
    stageA(0, 0, d0); stageA(0, 1, d0); stageA(0, 2, d0); stageA(0, 3, d0);
    if (NT > 1) {
        stageB(1, 0, d1); stageB(1, 1, d1); stageB(1, 2, d1); stageB(1, 3, d1);
        stageA(1, 1, d1); stageA(1, 3, d1);
    }
    asm volatile("s_waitcnt vmcnt(6)" ::: "memory");  // t0 complete (14 issued, 6 = t1's fly)
    __builtin_amdgcn_s_barrier();

    for (int kt = 0; kt < NT; ++kt) {
        char* db = lds + (kt & 1) * 65536;
        char* odb = lds + ((kt + 1) & 1) * 65536;
        half8 bfr[4][2];
#pragma unroll
        for (int p = 0; p < 4; ++p) {
            const int mb = 6 - 2 * p;           // descending m-pairs: a_hi first
            half8 afr[2][2];
#pragma unroll
            for (int mm = 0; mm < 2; ++mm) {
                int row = wr * 128 + (mb + mm) * 16 + lr;
                int u = row >> 6, r = row & 63;
#pragma unroll
                for (int kk = 0; kk < 2; ++kk)
                    afr[mm][kk] = *reinterpret_cast<const half8*>(
                        db + u * 8192 + r * 128 + ((((kk << 2) | lk)) ^ (r & 7)) * 16);
            }
            if (p == 0) {
#pragma unroll
                for (int n = 0; n < 4; ++n) {
                    int r = (wc * 64 + n * 16 + lr) & 63;
#pragma unroll
                    for (int kk = 0; kk < 2; ++kk)
                        bfr[n][kk] = *reinterpret_cast<const half8*>(
                            db + 32768 + wc * 8192 + r * 128 + ((((kk << 2) | lk)) ^ (r & 7)) * 16);
                }
            }
            __builtin_amdgcn_s_barrier();
            // stage (post-barrier: all waves' reads of target regions already issued+consumed)
            if (p == 0) {
                if (kt + 1 < NT) { stageA(kt + 1, 0, odb); stageA(kt + 1, 2, odb); }
            } else if (p == 1) {
                if (kt + 2 < NT) { stageB(kt + 2, 0, db); stageB(kt + 2, 1, db); }
            } else if (p == 2) {
                if (kt + 2 < NT) { stageB(kt + 2, 2, db); stageB(kt + 2, 3, db); }
            } else {
                if (kt + 2 < NT) { stageA(kt + 2, 1, db); stageA(kt + 2, 3, db); }
            }
            __builtin_amdgcn_s_setprio(1);
#pragma unroll
            for (int mm = 0; mm < 2; ++mm)
#pragma unroll
                for (int n = 0; n < 4; ++n)
#pragma unroll
                    for (int kk = 0; kk < 2; ++kk)
                        acc[mb + mm][n] = __builtin_amdgcn_mfma_f32_16x16x32_f16(
                            afr[mm][kk], bfr[n][kk], acc[mb + mm][n], 0, 0, 0);
            __builtin_amdgcn_s_setprio(0);
            if (p == 3) {
                if (kt + 2 < NT) asm volatile("s_waitcnt vmcnt(6)" ::: "memory");
                else             asm volatile("s_waitcnt vmcnt(0)" ::: "memory");
            }
            __builtin_amdgcn_s_barrier();
        }
    }

    // epilogue: relu(acc + bias) -> f16
#pragma unroll
    for (int n = 0; n < 4; ++n) {
        int col = n0 + wc * 64 + n * 16 + lr;
        float bv = bias[col];
#pragma unroll
        for (int m = 0; m < 8; ++m) {
            int rbase = bm * 256 + wr * 128 + m * 16 + lk * 4;
#pragma unroll
            for (int q = 0; q < 4; ++q) {
                float v = acc[m][n][q] + bv;
                v = v > 0.f ? v : 0.f;
                out[(size_t)(rbase + q) * H1D + col] = (_Float16)v;
            }
        }
    }
}

// ---------------- GEMM3 + sigmoid + LayerNorm: h2[E,512] x W3t[256,512] -> out[E,256] f32 ----
// BM=128 BN=256 (full width -> LN in-block), 512 thr = 8 waves (2x4), gload_lds staging

__global__ __launch_bounds__(512) void k_gemm3_ln(
    const _Float16* __restrict__ A, const _Float16* __restrict__ Wt,
    const float* __restrict__ bias, const float* __restrict__ gamma,
    const float* __restrict__ beta, float* __restrict__ out) {
    __shared__ __align__(16) _Float16 As[128][64];
    __shared__ __align__(16) _Float16 Bs[256][64];
    __shared__ float red1[128][4];
    __shared__ float red2[128][4];
    __shared__ float mvmu[128];
    __shared__ float mvrs[128];
    const int t = threadIdx.x;
    const int bm = blockIdx.x;
    const int w = t >> 6, lane = t & 63;
    const int wr = w >> 2, wc = w & 3, lr = lane & 15, lk = lane >> 4;

    const int srow = w * 8 + (lane >> 3);
    const int scol = (lane & 7) * 8;
    const _Float16* Ab = A + (size_t)(bm * 128 + srow) * H2D + scol;
    const _Float16* Bb = Wt + (size_t)srow * H2D + scol;

    f32x4 acc[4][4];
#pragma unroll
    for (int m = 0; m < 4; m++)
#pragma unroll
        for (int n = 0; n < 4; n++) acc[m][n] = (f32x4)0.f;

    for (int kt = 0; kt < 8; ++kt) {
        const int k0 = kt * 64;
        __syncthreads();
#pragma unroll
        for (int i = 0; i < 2; i++)
            gload16(Ab + (size_t)i * 64 * H2D + k0, (char*)As + i * 8192 + w * 1024);
#pragma unroll
        for (int i = 0; i < 4; i++)
            gload16(Bb + (size_t)i * 64 * H2D + k0, (char*)Bs + i * 8192 + w * 1024);
        __syncthreads();
#pragma unroll
        for (int kk = 0; kk < 2; kk++) {
            half8 a[4], b[4];
#pragma unroll
            for (int m = 0; m < 4; m++)
                a[m] = *reinterpret_cast<half8*>(&As[wr * 64 + m * 16 + lr][kk * 32 + lk * 8]);
#pragma unroll
            for (int n = 0; n < 4; n++)
                b[n] = *reinterpret_cast<half8*>(&Bs[wc * 64 + n * 16 + lr][kk * 32 + lk * 8]);
#pragma unroll
            for (int m = 0; m < 4; m++)
#pragma unroll
                for (int n = 0; n < 4; n++)
                    acc[m][n] = __builtin_amdgcn_mfma_f32_16x16x32_f16(a[m], b[n], acc[m][n], 0, 0, 0);
        }
    }

    // bias + sigmoid (fp32, h3 never hits HBM)
#pragma unroll
    for (int n = 0; n < 4; n++) {
        int col = wc * 64 + n * 16 + lr;
        float bv = bias[col];
#pragma unroll
        for (int m = 0; m < 4; m++)
#pragma unroll
            for (int q = 0; q < 4; q++) {
                float x = acc[m][n][q] + bv;
                acc[m][n][q] = 1.f / (1.f + __expf(-x));
            }
    }

    // LayerNorm over 256 cols
#pragma unroll
    for (int m = 0; m < 4; m++)
#pragma unroll
        for (int q = 0; q < 4; q++) {
            float s1 = 0.f, s2 = 0.f;
#pragma unroll
            for (int n = 0; n < 4; n++) {
                float x = acc[m][n][q];
                s1 += x; s2 += x * x;
            }
            s1 += __shfl_xor(s1, 1); s2 += __shfl_xor(s2, 1);
            s1 += __shfl_xor(s1, 2); s2 += __shfl_xor(s2, 2);
            s1 += __shfl_xor(s1, 4); s2 += __shfl_xor(s2, 4);
            s1 += __shfl_xor(s1, 8); s2 += __shfl_xor(s2, 8);
            if (lr == 0) {
                int row = wr * 64 + m * 16 + lk * 4 + q;
                red1[row][wc] = s1;
                red2[row][wc] = s2;
            }
        }
    __syncthreads();
    if (t < 128) {
        float s = red1[t][0] + red1[t][1] + red1[t][2] + red1[t][3];
        float ss = red2[t][0] + red2[t][1] + red2[t][2] + red2[t][3];
        float mu = s * (1.f / H3D);
        float var = ss * (1.f / H3D) - mu * mu;
        mvmu[t] = mu;
        mvrs[t] = rsqrtf(var + LN_EPS);
    }
    __syncthreads();
#pragma unroll
    for (int m = 0; m < 4; m++)
#pragma unroll
        for (int q = 0; q < 4; q++) {
            int row = wr * 64 + m * 16 + lk * 4 + q;
            float mu = mvmu[row], rs = mvrs[row];
#pragma unroll
            for (int n = 0; n < 4; n++) {
                int col = wc * 64 + n * 16 + lr;
                out[(size_t)(bm * 128 + row) * H3D + col] =
                    gamma[col] * (acc[m][n][q] - mu) * rs + beta[col];
            }
        }
}

// ---------------- launch ----------------

extern "C" void kernel_launch(void* const* d_in, const int* in_sizes, int n_in,
                              void* d_out, int out_size, void* d_ws, size_t ws_size,
                              hipStream_t stream) {
    const float* feat  = (const float*)d_in[0];
    const float* nodes = (const float*)d_in[1];
    const float* gfeat = (const float*)d_in[2];
    const int*   ind   = (const int*)d_in[3];
    const int*   num   = (const int*)d_in[4];
    const float* W1    = (const float*)d_in[5];
    const float* b1    = (const float*)d_in[6];
    const float* W2    = (const float*)d_in[7];
    const float* b2    = (const float*)d_in[8];
    const float* W3    = (const float*)d_in[9];
    const float* b3    = (const float*)d_in[10];
    const float* gamma = (const float*)d_in[11];
    const float* beta  = (const float*)d_in[12];
    float* out = (float*)d_out;

    char* ws = (char*)d_ws;
    size_t off = 0;
    auto alloc = [&](size_t bytes) {
        size_t o = off;
        off += (bytes + 255) & ~(size_t)255;
        return o;
    };
    int* prefix       = (int*)(ws + alloc((G_GRAPHS + 1) * sizeof(int)));
    int* gid          = (int*)(ws + alloc((size_t)E_EDGES * sizeof(int)));
    _Float16* W1t     = (_Float16*)(ws + alloc((size_t)H1D * D_IN * 2));
    _Float16* W2t     = (_Float16*)(ws + alloc((size_t)H2D * H1D * 2));
    _Float16* W3t     = (_Float16*)(ws + alloc((size_t)H3D * H2D * 2));
    _Float16* feat16  = (_Float16*)(ws + alloc((size_t)E_EDGES * D_EDGE * 2));
    _Float16* nodes16 = (_Float16*)(ws + alloc((size_t)N_NODES * D_NODE * 2));
    _Float16* gfeat16 = (_Float16*)(ws + alloc((size_t)G_GRAPHS * D_GLOB * 2));
    _Float16* h1      = (_Float16*)(ws + alloc((size_t)E_EDGES * H1D * 2));
    _Float16* h2      = (_Float16*)(ws + alloc((size_t)E_EDGES * H2D * 2));
    (void)ws_size; (void)in_sizes; (void)n_in; (void)out_size;

    k_prefix<<<1, 64, 0, stream>>>(num, prefix);
    k_gid<<<(E_EDGES + 255) / 256, 256, 0, stream>>>(prefix, gid);
    k_cvt16<<<2048, 256, 0, stream>>>(feat, feat16, (long)E_EDGES * D_EDGE / 8);
    k_cvt16<<<2048, 256, 0, stream>>>(nodes, nodes16, (long)N_NODES * D_NODE / 8);
    k_cvt16<<<16, 256, 0, stream>>>(gfeat, gfeat16, (long)G_GRAPHS * D_GLOB / 8);
    k_transpose<<<1024, 256, 0, stream>>>(W1, W1t, D_IN, H1D);
    k_transpose<<<512, 256, 0, stream>>>(W2, W2t, H1D, H2D);
    k_transpose<<<256, 256, 0, stream>>>(W3, W3t, H2D, H3D);
    k_gemm8<D_IN, true><<<dim3(H1D / 256, E_EDGES / 256), 512, 0, stream>>>(
        nullptr, feat16, nodes16, gfeat16, ind, gid, W1t, b1, h1);
    k_gemm8<H1D, false><<<dim3(H2D / 256, E_EDGES / 256), 512, 0, stream>>>(
        h1, nullptr, nullptr, nullptr, nullptr, nullptr, W2t, b2, h2);
    k_gemm3_ln<<<E_EDGES / 128, 512, 0, stream>>>(h2, W3t, b3, gamma, beta, out);
}

// Round 7
// 632.426 us; speedup vs baseline: 1.0265x; 1.0265x over previous
//
#include <hip/hip_runtime.h>
#include <hip/hip_fp16.h>

#define E_EDGES 102400
#define N_NODES 100000
#define G_GRAPHS 64
#define D_EDGE 256
#define D_NODE 256
#define D_GLOB 128
#define KNB 4
#define D_IN 1408   // 256 + 4*256 + 128
#define H1D 512
#define H2D 512
#define H3D 256
#define LN_EPS 1e-3f

typedef _Float16 half8 __attribute__((ext_vector_type(8)));
typedef float f32x4 __attribute__((ext_vector_type(4)));

// async global->LDS, 16B per lane; LDS dest wave-uniform base, HW adds lane*16
__device__ __forceinline__ void gload16(const void* g, void* l) {
    __builtin_amdgcn_global_load_lds((const __attribute__((address_space(1))) void*)g,
                                     (__attribute__((address_space(3))) void*)l, 16, 0, 0);
}

// ---------------- prep kernels (fused) ----------------

// prefix (recomputed per block in LDS, num is 64 ints) + per-edge graph id
__global__ void k_gid2(const int* __restrict__ num, int* __restrict__ gid) {
    __shared__ int pfx[G_GRAPHS + 1];
    if (threadIdx.x == 0) {
        int a = 0;
        pfx[0] = 0;
        for (int g = 0; g < G_GRAPHS; ++g) { a += num[g]; pfx[g + 1] = a; }
    }
    __syncthreads();
    int e = blockIdx.x * blockDim.x + threadIdx.x;
    if (e >= E_EDGES) return;
    int lo = 0, hi = G_GRAPHS;
    while (hi - lo > 1) {
        int mid = (lo + hi) >> 1;
        if (e >= pfx[mid]) lo = mid; else hi = mid;
    }
    gid[e] = lo;
}

// all three f32->f16 conversions in one grid-stride kernel
__global__ void k_cvtall(const float* __restrict__ feat, const float* __restrict__ nodes,
                         const float* __restrict__ gfeat,
                         _Float16* __restrict__ feat16, _Float16* __restrict__ nodes16,
                         _Float16* __restrict__ gfeat16) {
    const long c1 = (long)E_EDGES * D_EDGE / 8;
    const long c2 = c1 + (long)N_NODES * D_NODE / 8;
    const long c3 = c2 + (long)G_GRAPHS * D_GLOB / 8;
    for (long i = (long)blockIdx.x * blockDim.x + threadIdx.x; i < c3;
         i += (long)gridDim.x * blockDim.x) {
        const float* s;
        _Float16* d;
        long j;
        if (i < c1)      { s = feat;  d = feat16;  j = i; }
        else if (i < c2) { s = nodes; d = nodes16; j = i - c1; }
        else             { s = gfeat; d = gfeat16; j = i - c2; }
        float4 u = reinterpret_cast<const float4*>(s)[j * 2];
        float4 v = reinterpret_cast<const float4*>(s)[j * 2 + 1];
        half8 h;
        h[0] = (_Float16)u.x; h[1] = (_Float16)u.y; h[2] = (_Float16)u.z; h[3] = (_Float16)u.w;
        h[4] = (_Float16)v.x; h[5] = (_Float16)v.y; h[6] = (_Float16)v.z; h[7] = (_Float16)v.w;
        reinterpret_cast<half8*>(d)[j] = h;
    }
}

// LDS-tiled transpose+cvt for all three weights: dst[n*Ks+k] = (f16)src[k*Ns+n]
// 64x64 tiles, 256 thr (ty 0..3, tx 0..63): coalesced reads AND writes, +1-pad LDS.
__global__ __launch_bounds__(256) void k_wt(
    const float* __restrict__ W1, const float* __restrict__ W2, const float* __restrict__ W3,
    _Float16* __restrict__ W1t, _Float16* __restrict__ W2t, _Float16* __restrict__ W3t) {
    __shared__ float tile[64][65];
    int b = blockIdx.x;
    const float* src;
    _Float16* dst;
    int Ks, Ns, kt, nt;
    if (b < 176)      { src = W1; dst = W1t; Ks = D_IN; Ns = H1D; kt = b >> 3; nt = b & 7; }
    else if (b < 240) { b -= 176; src = W2; dst = W2t; Ks = H1D; Ns = H2D; kt = b >> 3; nt = b & 7; }
    else              { b -= 240; src = W3; dst = W3t; Ks = H2D; Ns = H3D; kt = b >> 2; nt = b & 3; }
    const int tx = threadIdx.x & 63, ty = threadIdx.x >> 6;
#pragma unroll
    for (int r = 0; r < 16; ++r) {
        int k = ty * 16 + r;
        tile[k][tx] = src[(size_t)(kt * 64 + k) * Ns + nt * 64 + tx];
    }
    __syncthreads();
#pragma unroll
    for (int r = 0; r < 16; ++r) {
        int n = ty * 16 + r;
        dst[(size_t)(nt * 64 + n) * Ks + kt * 64 + tx] = (_Float16)tile[tx][n];
    }
}

// ---------------- pipelined GEMM: [E,KD] x Wt[512,KD] -> relu -> out[E,512] f16 ----------------
// BM=128 BN=256 BK=64, 512 thr = 8 waves (2x4), per-wave 64x64.
// 3 LDS buffers (48KB each: A 16KB + B 32KB), depth-2 prefetch, counted vmcnt(6),
// raw s_barrier (1/iter). Stage at iter kt writes buf[(kt+2)%3] = buffer consumed at
// iter kt-1 -> no clobber by construction.
// T2 swizzle: LDS linear for gload_lds; GLOBAL source col pre-permuted slot^=(row&7);
// ds_read applies same XOR. T5 setprio around MFMA clusters.
// GATHER=true: A rows assembled from feat16/nodes16/gfeat16 via per-lane global addresses.

template <int KD, bool GATHER>
__global__ __launch_bounds__(512) void k_gemm_pipe(
    const _Float16* __restrict__ A,
    const _Float16* __restrict__ feat16, const _Float16* __restrict__ nodes16,
    const _Float16* __restrict__ gfeat16,
    const int* __restrict__ ind, const int* __restrict__ gid,
    const _Float16* __restrict__ Wt,
    const float* __restrict__ bias, _Float16* __restrict__ out) {
    constexpr int NT = KD / 64;
    __shared__ __align__(16) char lds[3 * 49152];  // 144 KB

    const int t = threadIdx.x;
    const int bn = blockIdx.x, bm = blockIdx.y;
    const int n0 = bn * 256;
    const int w = t >> 6, lane = t & 63;
    const int wr = w >> 2, wc = w & 3;          // 2 x 4 wave grid
    const int lr = lane & 15, lk = lane >> 4;

    const int srow = t >> 3;                    // 0..63
    const int gslot = (t & 7) ^ (srow & 7);     // pre-swizzled global slot
    const int wbase = w * 8;                    // wave-uniform row base within call

    int4 iv0, iv1;
    int g0 = 0, g1 = 0;
    int e0 = 0, e1 = 0;
    if constexpr (GATHER) {
        e0 = bm * 128 + srow;
        e1 = e0 + 64;
        iv0 = *reinterpret_cast<const int4*>(ind + (size_t)e0 * KNB);
        iv1 = *reinterpret_cast<const int4*>(ind + (size_t)e1 * KNB);
        g0 = gid[e0];
        g1 = gid[e1];
    }

    f32x4 acc[4][4];
#pragma unroll
    for (int m = 0; m < 4; m++)
#pragma unroll
        for (int n = 0; n < 4; n++) acc[m][n] = (f32x4)0.f;

    auto stage = [&](int kt, char* abuf, char* bbuf) {
#pragma unroll
        for (int c = 0; c < 2; ++c) {
            const _Float16* src;
            if constexpr (GATHER) {
                if (kt < 4) {
                    src = feat16 + (size_t)(c ? e1 : e0) * D_EDGE + kt * 64;
                } else if (kt < 20) {
                    int j = (kt - 4) >> 2;
                    int4 iv = c ? iv1 : iv0;
                    int nidx = j == 0 ? iv.x : j == 1 ? iv.y : j == 2 ? iv.z : iv.w;
                    src = nodes16 + (size_t)nidx * D_NODE + ((kt - 4) & 3) * 64;
                } else {
                    src = gfeat16 + (size_t)(c ? g1 : g0) * D_GLOB + (kt - 20) * 64;
                }
            } else {
                src = A + (size_t)(bm * 128 + c * 64 + srow) * KD + kt * 64;
            }
            gload16(src + gslot * 8, abuf + (c * 64 + wbase) * 128);
        }
#pragma unroll
        for (int c = 0; c < 4; ++c) {
            const _Float16* src = Wt + (size_t)(n0 + c * 64 + srow) * KD + kt * 64;
            gload16(src + gslot * 8, bbuf + (c * 64 + wbase) * 128);
        }
    };

    stage(0, lds, lds + 16384);
    stage(1, lds + 49152, lds + 49152 + 16384);
    asm volatile("s_waitcnt vmcnt(6)" ::: "memory");
    __builtin_amdgcn_s_barrier();

    int cur = 0;
    for (int kt = 0; kt < NT; ++kt) {
        const int pf = kt + 2;
        if (pf < NT) {
            const int pb = cur == 0 ? 2 : cur - 1;  // (cur+2)%3
            stage(pf, lds + pb * 49152, lds + pb * 49152 + 16384);
        }
        const char* ab = lds + cur * 49152;
        const char* bb = ab + 16384;
#pragma unroll
        for (int kk = 0; kk < 2; ++kk) {
            half8 a[4], b[4];
#pragma unroll
            for (int m = 0; m < 4; ++m) {
                int row = wr * 64 + m * 16 + lr;
                a[m] = *reinterpret_cast<const half8*>(
                    ab + row * 128 + ((((kk << 2) | lk)) ^ (lr & 7)) * 16);
            }
#pragma unroll
            for (int n = 0; n < 4; ++n) {
                int row = wc * 64 + n * 16 + lr;
                b[n] = *reinterpret_cast<const half8*>(
                    bb + row * 128 + ((((kk << 2) | lk)) ^ (lr & 7)) * 16);
            }
            __builtin_amdgcn_s_setprio(1);
#pragma unroll
            for (int m = 0; m < 4; ++m)
#pragma unroll
                for (int n = 0; n < 4; ++n)
                    acc[m][n] = __builtin_amdgcn_mfma_f32_16x16x32_f16(a[m], b[n], acc[m][n], 0, 0, 0);
            __builtin_amdgcn_s_setprio(0);
        }
        if (pf < NT) asm volatile("s_waitcnt vmcnt(6)" ::: "memory");
        else         asm volatile("s_waitcnt vmcnt(0)" ::: "memory");
        __builtin_amdgcn_s_barrier();
        cur = cur == 2 ? 0 : cur + 1;
    }

#pragma unroll
    for (int n = 0; n < 4; ++n) {
        int col = n0 + wc * 64 + n * 16 + lr;
        float bv = bias[col];
#pragma unroll
        for (int m = 0; m < 4; ++m) {
            int rbase = bm * 128 + wr * 64 + m * 16 + lk * 4;
#pragma unroll
            for (int q = 0; q < 4; ++q) {
                float v = acc[m][n][q] + bv;
                v = v > 0.f ? v : 0.f;
                out[(size_t)(rbase + q) * H1D + col] = (_Float16)v;
            }
        }
    }
}

// ---------------- GEMM3 (pipelined) + sigmoid + LayerNorm: h2[E,512] x W3t[256,512] -> out f32 ----
// Same 3-buffer pipeline; BM=128, BN=256 = full width so LN lives in-block. NT=8.

__global__ __launch_bounds__(512) void k_gemm3p(
    const _Float16* __restrict__ A, const _Float16* __restrict__ Wt,
    const float* __restrict__ bias, const float* __restrict__ gamma,
    const float* __restrict__ beta, float* __restrict__ out) {
    constexpr int NT = H2D / 64;  // 8
    __shared__ __align__(16) char lds[3 * 49152];
    __shared__ float red1[128][4];
    __shared__ float red2[128][4];
    __shared__ float mvmu[128];
    __shared__ float mvrs[128];

    const int t = threadIdx.x;
    const int bm = blockIdx.x;
    const int w = t >> 6, lane = t & 63;
    const int wr = w >> 2, wc = w & 3;
    const int lr = lane & 15, lk = lane >> 4;

    const int srow = t >> 3;
    const int gslot = (t & 7) ^ (srow & 7);
    const int wbase = w * 8;

    f32x4 acc[4][4];
#pragma unroll
    for (int m = 0; m < 4; m++)
#pragma unroll
        for (int n = 0; n < 4; n++) acc[m][n] = (f32x4)0.f;

    auto stage = [&](int kt, char* abuf, char* bbuf) {
#pragma unroll
        for (int c = 0; c < 2; ++c) {
            const _Float16* src = A + (size_t)(bm * 128 + c * 64 + srow) * H2D + kt * 64;
            gload16(src + gslot * 8, abuf + (c * 64 + wbase) * 128);
        }
#pragma unroll
        for (int c = 0; c < 4; ++c) {
            const _Float16* src = Wt + (size_t)(c * 64 + srow) * H2D + kt * 64;
            gload16(src + gslot * 8, bbuf + (c * 64 + wbase) * 128);
        }
    };

    stage(0, lds, lds + 16384);
    stage(1, lds + 49152, lds + 49152 + 16384);
    asm volatile("s_waitcnt vmcnt(6)" ::: "memory");
    __builtin_amdgcn_s_barrier();

    int cur = 0;
    for (int kt = 0; kt < NT; ++kt) {
        const int pf = kt + 2;
        if (pf < NT) {
            const int pb = cur == 0 ? 2 : cur - 1;
            stage(pf, lds + pb * 49152, lds + pb * 49152 + 16384);
        }
        const char* ab = lds + cur * 49152;
        const char* bb = ab + 16384;
#pragma unroll
        for (int kk = 0; kk < 2; ++kk) {
            half8 a[4], b[4];
#pragma unroll
            for (int m = 0; m < 4; ++m) {
                int row = wr * 64 + m * 16 + lr;
                a[m] = *reinterpret_cast<const half8*>(
                    ab + row * 128 + ((((kk << 2) | lk)) ^ (lr & 7)) * 16);
            }
#pragma unroll
            for (int n = 0; n < 4; ++n) {
                int row = wc * 64 + n * 16 + lr;
                b[n] = *reinterpret_cast<const half8*>(
                    bb + row * 128 + ((((kk << 2) | lk)) ^ (lr & 7)) * 16);
            }
            __builtin_amdgcn_s_setprio(1);
#pragma unroll
            for (int m = 0; m < 4; ++m)
#pragma unroll
                for (int n = 0; n < 4; ++n)
                    acc[m][n] = __builtin_amdgcn_mfma_f32_16x16x32_f16(a[m], b[n], acc[m][n], 0, 0, 0);
            __builtin_amdgcn_s_setprio(0);
        }
        if (pf < NT) asm volatile("s_waitcnt vmcnt(6)" ::: "memory");
        else         asm volatile("s_waitcnt vmcnt(0)" ::: "memory");
        __builtin_amdgcn_s_barrier();
        cur = cur == 2 ? 0 : cur + 1;
    }

    // bias + sigmoid (fp32, h3 never hits HBM)
#pragma unroll
    for (int n = 0; n < 4; n++) {
        int col = wc * 64 + n * 16 + lr;
        float bv = bias[col];
#pragma unroll
        for (int m = 0; m < 4; m++)
#pragma unroll
            for (int q = 0; q < 4; q++) {
                float x = acc[m][n][q] + bv;
                acc[m][n][q] = 1.f / (1.f + __expf(-x));
            }
    }

    // LayerNorm over 256 cols: 16-lane butterfly -> cross-wave LDS
#pragma unroll
    for (int m = 0; m < 4; m++)
#pragma unroll
        for (int q = 0; q < 4; q++) {
            float s1 = 0.f, s2 = 0.f;
#pragma unroll
            for (int n = 0; n < 4; n++) {
                float x = acc[m][n][q];
                s1 += x; s2 += x * x;
            }
            s1 += __shfl_xor(s1, 1); s2 += __shfl_xor(s2, 1);
            s1 += __shfl_xor(s1, 2); s2 += __shfl_xor(s2, 2);
            s1 += __shfl_xor(s1, 4); s2 += __shfl_xor(s2, 4);
            s1 += __shfl_xor(s1, 8); s2 += __shfl_xor(s2, 8);
            if (lr == 0) {
                int row = wr * 64 + m * 16 + lk * 4 + q;
                red1[row][wc] = s1;
                red2[row][wc] = s2;
            }
        }
    __syncthreads();
    if (t < 128) {
        float s = red1[t][0] + red1[t][1] + red1[t][2] + red1[t][3];
        float ss = red2[t][0] + red2[t][1] + red2[t][2] + red2[t][3];
        float mu = s * (1.f / H3D);
        float var = ss * (1.f / H3D) - mu * mu;
        mvmu[t] = mu;
        mvrs[t] = rsqrtf(var + LN_EPS);
    }
    __syncthreads();
#pragma unroll
    for (int m = 0; m < 4; m++)
#pragma unroll
        for (int q = 0; q < 4; q++) {
            int row = wr * 64 + m * 16 + lk * 4 + q;
            float mu = mvmu[row], rs = mvrs[row];
#pragma unroll
            for (int n = 0; n < 4; n++) {
                int col = wc * 64 + n * 16 + lr;
                out[(size_t)(bm * 128 + row) * H3D + col] =
                    gamma[col] * (acc[m][n][q] - mu) * rs + beta[col];
            }
        }
}

// ---------------- launch ----------------

extern "C" void kernel_launch(void* const* d_in, const int* in_sizes, int n_in,
                              void* d_out, int out_size, void* d_ws, size_t ws_size,
                              hipStream_t stream) {
    const float* feat  = (const float*)d_in[0];
    const float* nodes = (const float*)d_in[1];
    const float* gfeat = (const float*)d_in[2];
    const int*   ind   = (const int*)d_in[3];
    const int*   num   = (const int*)d_in[4];
    const float* W1    = (const float*)d_in[5];
    const float* b1    = (const float*)d_in[6];
    const float* W2    = (const float*)d_in[7];
    const float* b2    = (const float*)d_in[8];
    const float* W3    = (const float*)d_in[9];
    const float* b3    = (const float*)d_in[10];
    const float* gamma = (const float*)d_in[11];
    const float* beta  = (const float*)d_in[12];
    float* out = (float*)d_out;

    char* ws = (char*)d_ws;
    size_t off = 0;
    auto alloc = [&](size_t bytes) {
        size_t o = off;
        off += (bytes + 255) & ~(size_t)255;
        return o;
    };
    int* gid          = (int*)(ws + alloc((size_t)E_EDGES * sizeof(int)));
    _Float16* W1t     = (_Float16*)(ws + alloc((size_t)H1D * D_IN * 2));
    _Float16* W2t     = (_Float16*)(ws + alloc((size_t)H2D * H1D * 2));
    _Float16* W3t     = (_Float16*)(ws + alloc((size_t)H3D * H2D * 2));
    _Float16* feat16  = (_Float16*)(ws + alloc((size_t)E_EDGES * D_EDGE * 2));
    _Float16* nodes16 = (_Float16*)(ws + alloc((size_t)N_NODES * D_NODE * 2));
    _Float16* gfeat16 = (_Float16*)(ws + alloc((size_t)G_GRAPHS * D_GLOB * 2));
    _Float16* h1      = (_Float16*)(ws + alloc((size_t)E_EDGES * H1D * 2));
    _Float16* h2      = (_Float16*)(ws + alloc((size_t)E_EDGES * H2D * 2));
    (void)ws_size; (void)in_sizes; (void)n_in; (void)out_size;

    k_gid2<<<(E_EDGES + 255) / 256, 256, 0, stream>>>(num, gid);
    k_cvtall<<<2048, 256, 0, stream>>>(feat, nodes, gfeat, feat16, nodes16, gfeat16);
    k_wt<<<272, 256, 0, stream>>>(W1, W2, W3, W1t, W2t, W3t);
    k_gemm_pipe<D_IN, true><<<dim3(H1D / 256, E_EDGES / 128), 512, 0, stream>>>(
        nullptr, feat16, nodes16, gfeat16, ind, gid, W1t, b1, h1);
    k_gemm_pipe<H1D, false><<<dim3(H2D / 256, E_EDGES / 128), 512, 0, stream>>>(
        h1, nullptr, nullptr, nullptr, nullptr, nullptr, W2t, b2, h2);
    k_gemm3p<<<E_EDGES / 128, 512, 0, stream>>>(h2, W3t, b3, gamma, beta, out);
}